// Round 15
// baseline (1268.858 us; speedup 1.0000x reference)
//
#include <hip/hip_runtime.h>
#include <hip/hip_bf16.h>
#include <math.h>

// Problem constants
#define B_ 64
#define T_ 50
#define H_ 256
#define G_ 1024
#define V_ 50000
#define NBLK 32
#define BSTRIDE 64                      // ints per barrier slot (256B line)

using f16x8 = __attribute__((ext_vector_type(8))) _Float16;
using f16x4 = __attribute__((ext_vector_type(4))) _Float16;
using f32x4 = __attribute__((ext_vector_type(4))) float;

__device__ __forceinline__ float sigm(float x) { return 1.0f / (1.0f + expf(-x)); }

// ---------------------------------------------------------------------------
// Embedding gather -> fp16, time-major: x16[t*B + b][h]
// ---------------------------------------------------------------------------
__global__ __launch_bounds__(64) void embed_k(const int* __restrict__ idx,
                                              const float* __restrict__ emb,
                                              _Float16* __restrict__ x16)
{
    const int row = blockIdx.x;          // t*B + b
    const int b = row & (B_ - 1);
    const int t = row >> 6;
    const int id = idx[b * T_ + t];
    const float4 v = *reinterpret_cast<const float4*>(emb + (size_t)id * H_ + threadIdx.x * 4);
    f16x4 h;
    h[0] = (_Float16)v.x; h[1] = (_Float16)v.y;
    h[2] = (_Float16)v.z; h[3] = (_Float16)v.w;
    *reinterpret_cast<f16x4*>(x16 + (size_t)row * H_ + threadIdx.x * 4) = h;
}

// ---------------------------------------------------------------------------
// fp32 -> fp16 convert (8 elems/thread), n multiple of 2048
// ---------------------------------------------------------------------------
__global__ __launch_bounds__(256) void conv_half(const float* __restrict__ in,
                                                 _Float16* __restrict__ out, int n)
{
    const int i = (blockIdx.x * 256 + threadIdx.x) * 8;
    if (i + 8 <= n) {
        const float4 v0 = *reinterpret_cast<const float4*>(in + i);
        const float4 v1 = *reinterpret_cast<const float4*>(in + i + 4);
        f16x8 h;
        h[0] = (_Float16)v0.x; h[1] = (_Float16)v0.y;
        h[2] = (_Float16)v0.z; h[3] = (_Float16)v0.w;
        h[4] = (_Float16)v1.x; h[5] = (_Float16)v1.y;
        h[6] = (_Float16)v1.z; h[7] = (_Float16)v1.w;
        *reinterpret_cast<f16x8*>(out + i) = h;
    }
}

// ---------------------------------------------------------------------------
// Transpose-pack Wx[0] [256][1024] fp32 -> wxT [1024][256] fp16.
// ---------------------------------------------------------------------------
__global__ __launch_bounds__(256) void pack_wx0(const float* __restrict__ Wx0,
                                                _Float16* __restrict__ wxT)
{
    __shared__ _Float16 ts[64][65];
    const int k0 = blockIdx.x * 64;
    const int n0 = blockIdx.y * 64;
    const int tr = threadIdx.x >> 6;     // 0..3
    const int tc = threadIdx.x & 63;
#pragma unroll
    for (int i = 0; i < 16; ++i) {
        const int r = i * 4 + tr;
        ts[r][tc] = (_Float16)Wx0[(size_t)(k0 + r) * G_ + n0 + tc];
    }
    __syncthreads();
#pragma unroll
    for (int i = 0; i < 16; ++i) {
        const int c = i * 4 + tr;
        wxT[(size_t)(n0 + c) * H_ + k0 + tc] = ts[tc][c];
    }
}

// ---------------------------------------------------------------------------
// Pack recurrence weights for column-partitioned blocks.
// ---------------------------------------------------------------------------
__global__ __launch_bounds__(256) void pack_w_rec(const float* __restrict__ Uh0,
                                                  const float* __restrict__ Wx1,
                                                  const float* __restrict__ Uh1,
                                                  _Float16* __restrict__ wpk)
{
    const int c = blockIdx.x;            // 0..31
    const int m = blockIdx.y;            // 0..2
    const float* __restrict__ src = (m == 0) ? Uh0 : (m == 1) ? Wx1 : Uh1;
    _Float16* __restrict__ dst = wpk + (((size_t)c * 3 + m) << 13);
    for (int i = threadIdx.x; i < 8192; i += 256) {
        const int k = i >> 5;
        const int col = i & 31;
        const int colg = ((col >> 3) << 8) + (c << 3) + (col & 7);
        dst[(col << 8) + k] = (_Float16)src[(size_t)k * G_ + colg];
    }
}

// ---------------------------------------------------------------------------
__device__ __forceinline__ void gload_lds16(const void* g, void* l)
{
    __builtin_amdgcn_global_load_lds(
        (const __attribute__((address_space(1))) unsigned int*)g,
        (__attribute__((address_space(3))) unsigned int*)l, 16, 0, 0);
}

// ---------------------------------------------------------------------------
// xh0 GEMM via fp16 MFMA: xh0[3200][1024] = x16[3200][256] @ wxT[1024][256]^T
// ---------------------------------------------------------------------------
#define PM 128
#define PN 128
#define PK 64

__global__ __launch_bounds__(256) void gemm16_mfma(
    const _Float16* __restrict__ A16,   // [3200][256]
    const _Float16* __restrict__ B16,   // [1024][256]
    float* __restrict__ C)              // [3200][1024]
{
    __shared__ __align__(16) _Float16 Asub[PM * PK];
    __shared__ __align__(16) _Float16 Bsub[PN * PK];

    const int tid = threadIdx.x;
    const int l = tid & 63;
    const int w = tid >> 6;
    const int wm = w >> 1, wn = w & 1;

    const int n0 = blockIdx.x * PN;
    const int m0 = blockIdx.y * PM;

    f32x4 acc[4][4] = {};

    for (int k0 = 0; k0 < H_; k0 += PK) {
#pragma unroll
        for (int is = 0; is < 4; ++is) {
            const int i = is * 256 + tid;
            const int r = i >> 3;
            const int ch = (i & 7) ^ (r & 7);
            gload_lds16(A16 + (size_t)(m0 + r) * H_ + k0 + ch * 8, &Asub[i * 8]);
            gload_lds16(B16 + (size_t)(n0 + r) * H_ + k0 + ch * 8, &Bsub[i * 8]);
        }
        __syncthreads();

#pragma unroll
        for (int ks = 0; ks < 2; ++ks) {
            f16x8 af[4], bf[4];
#pragma unroll
            for (int i = 0; i < 4; ++i) {
                const int r = wm * 64 + i * 16 + (l & 15);
                const int ch = (ks * 4 + (l >> 4)) ^ (r & 7);
                af[i] = *reinterpret_cast<const f16x8*>(&Asub[r * PK + ch * 8]);
            }
#pragma unroll
            for (int jf = 0; jf < 4; ++jf) {
                const int r = wn * 64 + jf * 16 + (l & 15);
                const int ch = (ks * 4 + (l >> 4)) ^ (r & 7);
                bf[jf] = *reinterpret_cast<const f16x8*>(&Bsub[r * PK + ch * 8]);
            }
#pragma unroll
            for (int i = 0; i < 4; ++i)
#pragma unroll
                for (int jf = 0; jf < 4; ++jf)
                    acc[i][jf] = __builtin_amdgcn_mfma_f32_16x16x32_f16(
                        af[i], bf[jf], acc[i][jf], 0, 0, 0);
        }
        __syncthreads();
    }

    const int rb = (l >> 4) << 2;
    const int cl = l & 15;
#pragma unroll
    for (int jf = 0; jf < 4; ++jf) {
        const int col = n0 + wn * 64 + jf * 16 + cl;
#pragma unroll
        for (int i = 0; i < 4; ++i) {
            const int rowb = m0 + wm * 64 + i * 16 + rb;
#pragma unroll
            for (int r = 0; r < 4; ++r)
                C[(size_t)(rowb + r) * G_ + col] = acc[i][jf][r];
        }
    }
}

// ---------------------------------------------------------------------------
// Column-partitioned persistent MI-LSTM recurrence, FENCELESS exchange:
// h slices move via write-through/read-through u32 agent-scope atomics;
// block c's slice lives at [(c<<8) + tid] (disjoint per block — the round-14
// bug was omitting this offset). No __threadfence.
// ---------------------------------------------------------------------------
__global__ __launch_bounds__(256) void mi_rec(
    const _Float16* __restrict__ wpk,   // [32][3][32][256]
    const float* __restrict__ xh0,      // [T*B][G] fp32
    unsigned int* __restrict__ h0s,     // [2][32][256] u32 compact slices
    unsigned int* __restrict__ h1s,     // [2][32][256]
    _Float16* __restrict__ outsH,       // [B*T][H] batch-major
    int* __restrict__ bars,             // padded slots, zeroed
    const float* __restrict__ alpha, const float* __restrict__ b1,
    const float* __restrict__ b2, const float* __restrict__ bsv)
{
    __shared__ __align__(16) _Float16 h0l[16384];   // [64][256] swizzled
    __shared__ __align__(16) _Float16 h1l[16384];
    __shared__ __align__(16) _Float16 wl[24576];    // [3][32][256] swizzled
    __shared__ float gA[2112], gB[2112];            // [64][33]
    __shared__ float c0l[512], c1l[512];
    __shared__ _Float16 htmp[512];                  // [64][8] pack staging

    const int c = blockIdx.x;
    const int tid = threadIdx.x;
    const int l = tid & 63;
    const int w = tid >> 6;

    for (int i = tid; i < 2048; i += 256) {
        *reinterpret_cast<f16x8*>(&h0l[i << 3]) = f16x8{};
        *reinterpret_cast<f16x8*>(&h1l[i << 3]) = f16x8{};
    }
    for (int i = tid; i < 512; i += 256) { c0l[i] = 0.f; c1l[i] = 0.f; }

    for (int i = tid; i < 3072; i += 256) {
        const int m = i >> 10;
        const int col = (i >> 5) & 31;
        const int ch = i & 31;
        const f16x8 v = *reinterpret_cast<const f16x8*>(
            &wpk[(((size_t)c * 3 + m) * 32 + col) * 256 + (ch << 3)]);
        *reinterpret_cast<f16x8*>(
            &wl[(m * 32 + col) * 256 + ((ch ^ (col & 7)) << 3)]) = v;
    }

    const int u = tid & 7, b0 = tid >> 3;
    const int jl = (c << 3) + u;
    float al0[4], b10[4], b20[4], bs0[4], al1[4], b11[4], b21[4], bs1[4];
#pragma unroll
    for (int g = 0; g < 4; ++g) {
        const int col = (g << 8) + jl;
        al0[g] = alpha[col];        b10[g] = b1[col];
        b20[g] = b2[col];           bs0[g] = bsv[col];
        al1[g] = alpha[G_ + col];   b11[g] = b1[G_ + col];
        b21[g] = b2[G_ + col];      bs1[g] = bsv[G_ + col];
    }
    __syncthreads();

    const int arow = (w << 4) + (l & 15);
    const int cA = l & 15, cB = 16 + (l & 15);
    const int kq = l >> 4;
    const int pb = tid >> 2, pq = tid & 3;          // pack/unpack roles
    const unsigned short* htu = reinterpret_cast<const unsigned short*>(htmp);

    auto MM = [&](const _Float16* am, const _Float16* bm, f32x4& A0, f32x4& A1) {
#pragma unroll
        for (int s = 0; s < 8; ++s) {
            const int ck = (s << 2) + kq;
            const f16x8 af = *reinterpret_cast<const f16x8*>(
                &am[(arow << 8) + ((ck ^ (arow & 7)) << 3)]);
            const f16x8 bf0 = *reinterpret_cast<const f16x8*>(
                &bm[(cA << 8) + ((ck ^ (cA & 7)) << 3)]);
            const f16x8 bf1 = *reinterpret_cast<const f16x8*>(
                &bm[(cB << 8) + ((ck ^ (cB & 7)) << 3)]);
            A0 = __builtin_amdgcn_mfma_f32_16x16x32_f16(af, bf0, A0, 0, 0, 0);
            A1 = __builtin_amdgcn_mfma_f32_16x16x32_f16(af, bf1, A1, 0, 0, 0);
        }
    };
    auto STG = [&](float* gl, f32x4 A0, f32x4 A1) {
        const int rb = (w << 4) + (kq << 2);
#pragma unroll
        for (int r = 0; r < 4; ++r) {
            gl[(rb + r) * 33 + cA] = A0[r];
            gl[(rb + r) * 33 + cB] = A1[r];
        }
    };
    // pack own slice [64][8] fp16 -> 256 u32, write-through at (c<<8)+tid
    auto PACK_STORE = [&](unsigned int* dst) {
        const unsigned int lo = htu[(pb << 3) + (pq << 1)];
        const unsigned int hi = htu[(pb << 3) + (pq << 1) + 1];
        __hip_atomic_store(&dst[(c << 8) + tid], lo | (hi << 16),
                           __ATOMIC_RELAXED, __HIP_MEMORY_SCOPE_AGENT);
    };
    // gather 32 slices -> swizzled LDS [64][256]
    auto READ_STAGE = [&](const unsigned int* src, _Float16* dst) {
#pragma unroll
        for (int cc = 0; cc < 32; ++cc) {
            const unsigned int v = __hip_atomic_load(&src[(cc << 8) + tid],
                                   __ATOMIC_RELAXED, __HIP_MEMORY_SCOPE_AGENT);
            *reinterpret_cast<unsigned int*>(
                reinterpret_cast<char*>(dst) + (pb << 9)
                + ((cc ^ (pb & 7)) << 4) + (pq << 2)) = v;
        }
    };

    for (int s = 0; s <= T_; ++s) {
        const int p = s & 1;
        unsigned int* h0d = h0s + (p << 13);
        unsigned int* h1d = h1s + (p << 13);

        if (s < T_) {
            // hoist xh0 loads (hide L3 latency under MM)
            float xv[2][4];
#pragma unroll
            for (int bb = 0; bb < 2; ++bb)
#pragma unroll
                for (int g = 0; g < 4; ++g)
                    xv[bb][g] = xh0[(((size_t)(s * B_ + (b0 + (bb << 5)))) << 10)
                                    + (g << 8) + jl];

            f32x4 A0 = {}, A1 = {};
            MM(h0l, wl, A0, A1);                 // Uh0
            STG(gA, A0, A1);
            __syncthreads();
#pragma unroll
            for (int bb = 0; bb < 2; ++bb) {
                const int b = b0 + (bb << 5);
                float g4[4];
#pragma unroll
                for (int g = 0; g < 4; ++g) {
                    const float a = gA[b * 33 + (g << 3) + u];
                    const float x = xv[bb][g];
                    g4[g] = al0[g] * x * a + b10[g] * x + b20[g] * a + bs0[g];
                }
                const float cn = c0l[(b << 3) + u] * sigm(g4[2] + 1.f)
                               + sigm(g4[0]) * tanhf(g4[1]);
                c0l[(b << 3) + u] = cn;
                htmp[(b << 3) + u] = (_Float16)(tanhf(cn) * sigm(g4[3]));
            }
            __syncthreads();
            PACK_STORE(h0d);
        }

        if (s > 0) {
            f32x4 X0 = {}, X1 = {}, H0 = {}, H1 = {};
            MM(h0l, wl + 1 * 8192, X0, X1);      // Wx1 * h0(s-1)
            MM(h1l, wl + 2 * 8192, H0, H1);      // Uh1 * h1(s-2)
            STG(gA, X0, X1);
            STG(gB, H0, H1);
            __syncthreads();
#pragma unroll
            for (int bb = 0; bb < 2; ++bb) {
                const int b = b0 + (bb << 5);
                float g4[4];
#pragma unroll
                for (int g = 0; g < 4; ++g) {
                    const float xa = gA[b * 33 + (g << 3) + u];
                    const float ha = gB[b * 33 + (g << 3) + u];
                    g4[g] = al1[g] * xa * ha + b11[g] * xa + b21[g] * ha + bs1[g];
                }
                const float cn = c1l[(b << 3) + u] * sigm(g4[2] + 1.f)
                               + sigm(g4[0]) * tanhf(g4[1]);
                c1l[(b << 3) + u] = cn;
                const float hn = tanhf(cn) * sigm(g4[3]);
                htmp[(b << 3) + u] = (_Float16)hn;
                outsH[(((size_t)b * T_ + (s - 1)) << 8) + jl] = (_Float16)hn;
            }
            __syncthreads();
            PACK_STORE(h1d);
        }

        if (s < T_) {
            // arrive: __syncthreads drains each wave's vmem, then flag
            __syncthreads();
            if (tid == 0)
                __hip_atomic_fetch_add(&bars[s * BSTRIDE], 1,
                                       __ATOMIC_RELAXED, __HIP_MEMORY_SCOPE_AGENT);
            if (tid == 0) {
                while (__hip_atomic_load(&bars[s * BSTRIDE],
                        __ATOMIC_RELAXED, __HIP_MEMORY_SCOPE_AGENT) < NBLK)
                    __builtin_amdgcn_s_sleep(1);
            }
            __syncthreads();
            asm volatile("" ::: "memory");
            READ_STAGE(h0s + (p << 13), h0l);
            if (s > 0) READ_STAGE(h1s + (p << 13), h1l);
            __syncthreads();
        }
    }
}

// ---------------------------------------------------------------------------
// Projection: out[3200][50000] = outsH @ w16^T + sb.  fp16 MFMA, 128x128 tile.
// grid (25, 391): mt fastest for B-panel sharing.
// ---------------------------------------------------------------------------
__global__ __launch_bounds__(256) void proj_mfma(
    const _Float16* __restrict__ A16,   // [3200][256]
    const _Float16* __restrict__ B16,   // [50000][256]
    const float* __restrict__ bias,     // [50000]
    float* __restrict__ C)              // [3200][50000]
{
    __shared__ __align__(16) _Float16 Asub[PM * PK];
    __shared__ __align__(16) _Float16 Bsub[PN * PK];

    const int tid = threadIdx.x;
    const int l = tid & 63;
    const int w = tid >> 6;
    const int wm = w >> 1, wn = w & 1;

    const int m0 = blockIdx.x * PM;
    const int n0 = blockIdx.y * PN;

    f32x4 acc[4][4] = {};

    for (int k0 = 0; k0 < H_; k0 += PK) {
#pragma unroll
        for (int is = 0; is < 4; ++is) {
            const int i = is * 256 + tid;
            const int r = i >> 3;
            const int ch = (i & 7) ^ (r & 7);
            gload_lds16(A16 + (size_t)(m0 + r) * H_ + k0 + ch * 8, &Asub[i * 8]);
            int n = n0 + r; if (n > V_ - 1) n = V_ - 1;
            gload_lds16(B16 + (size_t)n * H_ + k0 + ch * 8, &Bsub[i * 8]);
        }
        __syncthreads();

#pragma unroll
        for (int ks = 0; ks < 2; ++ks) {
            f16x8 af[4], bf[4];
#pragma unroll
            for (int i = 0; i < 4; ++i) {
                const int r = wm * 64 + i * 16 + (l & 15);
                const int ch = (ks * 4 + (l >> 4)) ^ (r & 7);
                af[i] = *reinterpret_cast<const f16x8*>(&Asub[r * PK + ch * 8]);
            }
#pragma unroll
            for (int jf = 0; jf < 4; ++jf) {
                const int r = wn * 64 + jf * 16 + (l & 15);
                const int ch = (ks * 4 + (l >> 4)) ^ (r & 7);
                bf[jf] = *reinterpret_cast<const f16x8*>(&Bsub[r * PK + ch * 8]);
            }
#pragma unroll
            for (int i = 0; i < 4; ++i)
#pragma unroll
                for (int jf = 0; jf < 4; ++jf)
                    acc[i][jf] = __builtin_amdgcn_mfma_f32_16x16x32_f16(
                        af[i], bf[jf], acc[i][jf], 0, 0, 0);
        }
        __syncthreads();
    }

    const int rb = (l >> 4) << 2;
    const int cl = l & 15;
#pragma unroll
    for (int jf = 0; jf < 4; ++jf) {
        const int col = n0 + wn * 64 + jf * 16 + cl;
        if (col < V_) {
            const float bv = bias[col];
#pragma unroll
            for (int i = 0; i < 4; ++i) {
                const int rowb = m0 + wm * 64 + i * 16 + rb;
#pragma unroll
                for (int r = 0; r < 4; ++r)
                    C[(size_t)(rowb + r) * V_ + col] = acc[i][jf][r] + bv;
            }
        }
    }
}

// ---------------------------------------------------------------------------
extern "C" void kernel_launch(void* const* d_in, const int* in_sizes, int n_in,
                              void* d_out, int out_size, void* d_ws, size_t ws_size,
                              hipStream_t stream)
{
    const int*   idx   = (const int*)  d_in[0];
    const float* emb   = (const float*)d_in[1];
    const float* Wx    = (const float*)d_in[2];   // [2][256][1024]
    const float* Uh    = (const float*)d_in[3];   // [2][256][1024]
    const float* alpha = (const float*)d_in[4];   // [2][1024]
    const float* b1    = (const float*)d_in[5];
    const float* b2    = (const float*)d_in[6];
    const float* bsv   = (const float*)d_in[7];
    const float* sw    = (const float*)d_in[8];   // [50000][256]
    const float* sb    = (const float*)d_in[9];   // [50000]
    float* out = (float*)d_out;

    // workspace layout (bytes)
    char* wsb = (char*)d_ws;
    _Float16*     x16   = (_Float16*)    (wsb);                 //  1,638,400
    float*        xh0   = (float*)       (wsb + 1638400);       // 13,107,200
    _Float16*     outsH = (_Float16*)    (wsb + 14745600);      //  1,638,400
    _Float16*     w16   = (_Float16*)    (wsb + 16384000);      // 25,600,000
    _Float16*     wxT   = (_Float16*)    (wsb + 41984000);      //    524,288
    _Float16*     wpk   = (_Float16*)    (wsb + 42508288);      //  1,572,864
    unsigned int* h0s   = (unsigned int*)(wsb + 44081152);      //     65,536
    unsigned int* h1s   = (unsigned int*)(wsb + 44146688);      //     65,536
    int*          bars  = (int*)         (wsb + 44212224);      //     16,384

    const float* Wx0 = Wx;
    const float* Wx1 = Wx + (size_t)H_ * G_;
    const float* Uh0 = Uh;
    const float* Uh1 = Uh + (size_t)H_ * G_;

    // zero barrier slots (must precede mi_rec every call)
    (void)hipMemsetAsync(bars, 0, 16384, stream);

    // 0) pack recurrence weights + transpose-pack Wx0 + w16 convert
    {
        dim3 grid(NBLK, 3);
        pack_w_rec<<<grid, 256, 0, stream>>>(Uh0, Wx1, Uh1, wpk);
    }
    {
        dim3 grid(4, 16);
        pack_wx0<<<grid, 256, 0, stream>>>(Wx0, wxT);
    }
    conv_half<<<(V_ * H_) / 2048, 256, 0, stream>>>(sw, w16, V_ * H_);

    // 1) embedding gather -> fp16 (time-major)
    embed_k<<<T_ * B_, 64, 0, stream>>>(idx, emb, x16);

    // 2) xh0 = x16 @ wxT^T  (fp16 MFMA, fp32 out)
    {
        dim3 grid(G_ / PN, 3200 / PM);   // (8, 25)
        gemm16_mfma<<<grid, 256, 0, stream>>>(x16, wxT, xh0);
    }

    // 3) recurrence: 32-block cooperative persistent kernel (fenceless)
    mi_rec<<<NBLK, 256, 0, stream>>>(wpk, xh0, h0s, h1s, outsH, bars,
                                     alpha, b1, b2, bsv);

    // 4) logits = outsH @ w16^T + sb
    {
        dim3 grid(3200 / PM, (V_ + PN - 1) / PN);   // (25, 391)
        proj_mfma<<<grid, 256, 0, stream>>>(outsH, w16, sb, out);
    }
}

// Round 16
// 692.635 us; speedup vs baseline: 1.8319x; 1.8319x over previous
//
#include <hip/hip_runtime.h>
#include <hip/hip_bf16.h>
#include <math.h>

// Problem constants
#define B_ 64
#define T_ 50
#define H_ 256
#define G_ 1024
#define V_ 50000
#define NBLK 32
#define BSTRIDE 64                      // ints per barrier slot (256B line)

using f16x8 = __attribute__((ext_vector_type(8))) _Float16;
using f16x4 = __attribute__((ext_vector_type(4))) _Float16;
using f32x4 = __attribute__((ext_vector_type(4))) float;

__device__ __forceinline__ float sigm(float x) { return 1.0f / (1.0f + expf(-x)); }

// ---------------------------------------------------------------------------
// Embedding gather -> fp16, time-major: x16[t*B + b][h]
// ---------------------------------------------------------------------------
__global__ __launch_bounds__(64) void embed_k(const int* __restrict__ idx,
                                              const float* __restrict__ emb,
                                              _Float16* __restrict__ x16)
{
    const int row = blockIdx.x;          // t*B + b
    const int b = row & (B_ - 1);
    const int t = row >> 6;
    const int id = idx[b * T_ + t];
    const float4 v = *reinterpret_cast<const float4*>(emb + (size_t)id * H_ + threadIdx.x * 4);
    f16x4 h;
    h[0] = (_Float16)v.x; h[1] = (_Float16)v.y;
    h[2] = (_Float16)v.z; h[3] = (_Float16)v.w;
    *reinterpret_cast<f16x4*>(x16 + (size_t)row * H_ + threadIdx.x * 4) = h;
}

// ---------------------------------------------------------------------------
// fp32 -> fp16 convert (8 elems/thread), n multiple of 2048
// ---------------------------------------------------------------------------
__global__ __launch_bounds__(256) void conv_half(const float* __restrict__ in,
                                                 _Float16* __restrict__ out, int n)
{
    const int i = (blockIdx.x * 256 + threadIdx.x) * 8;
    if (i + 8 <= n) {
        const float4 v0 = *reinterpret_cast<const float4*>(in + i);
        const float4 v1 = *reinterpret_cast<const float4*>(in + i + 4);
        f16x8 h;
        h[0] = (_Float16)v0.x; h[1] = (_Float16)v0.y;
        h[2] = (_Float16)v0.z; h[3] = (_Float16)v0.w;
        h[4] = (_Float16)v1.x; h[5] = (_Float16)v1.y;
        h[6] = (_Float16)v1.z; h[7] = (_Float16)v1.w;
        *reinterpret_cast<f16x8*>(out + i) = h;
    }
}

// ---------------------------------------------------------------------------
// Transpose-pack Wx[0] [256][1024] fp32 -> wxT [1024][256] fp16.
// ---------------------------------------------------------------------------
__global__ __launch_bounds__(256) void pack_wx0(const float* __restrict__ Wx0,
                                                _Float16* __restrict__ wxT)
{
    __shared__ _Float16 ts[64][65];
    const int k0 = blockIdx.x * 64;
    const int n0 = blockIdx.y * 64;
    const int tr = threadIdx.x >> 6;     // 0..3
    const int tc = threadIdx.x & 63;
#pragma unroll
    for (int i = 0; i < 16; ++i) {
        const int r = i * 4 + tr;
        ts[r][tc] = (_Float16)Wx0[(size_t)(k0 + r) * G_ + n0 + tc];
    }
    __syncthreads();
#pragma unroll
    for (int i = 0; i < 16; ++i) {
        const int c = i * 4 + tr;
        wxT[(size_t)(n0 + c) * H_ + k0 + tc] = ts[tc][c];
    }
}

// ---------------------------------------------------------------------------
// Pack recurrence weights for column-partitioned blocks.
// ---------------------------------------------------------------------------
__global__ __launch_bounds__(256) void pack_w_rec(const float* __restrict__ Uh0,
                                                  const float* __restrict__ Wx1,
                                                  const float* __restrict__ Uh1,
                                                  _Float16* __restrict__ wpk)
{
    const int c = blockIdx.x;            // 0..31
    const int m = blockIdx.y;            // 0..2
    const float* __restrict__ src = (m == 0) ? Uh0 : (m == 1) ? Wx1 : Uh1;
    _Float16* __restrict__ dst = wpk + (((size_t)c * 3 + m) << 13);
    for (int i = threadIdx.x; i < 8192; i += 256) {
        const int k = i >> 5;
        const int col = i & 31;
        const int colg = ((col >> 3) << 8) + (c << 3) + (col & 7);
        dst[(col << 8) + k] = (_Float16)src[(size_t)k * G_ + colg];
    }
}

// ---------------------------------------------------------------------------
__device__ __forceinline__ void gload_lds16(const void* g, void* l)
{
    __builtin_amdgcn_global_load_lds(
        (const __attribute__((address_space(1))) unsigned int*)g,
        (__attribute__((address_space(3))) unsigned int*)l, 16, 0, 0);
}

// Barrier slots padded: slot s at bars + s*BSTRIDE.
__device__ __forceinline__ void gbar_arrive(int* slot)
{
    __syncthreads();
    if (threadIdx.x == 0) {
        __threadfence();
        __hip_atomic_fetch_add(slot, 1, __ATOMIC_RELAXED, __HIP_MEMORY_SCOPE_AGENT);
    }
}

__device__ __forceinline__ void gbar_wait_fast(int* slot)
{
    if (threadIdx.x == 0) {
        while (__hip_atomic_load(slot, __ATOMIC_RELAXED, __HIP_MEMORY_SCOPE_AGENT) < NBLK)
            __builtin_amdgcn_s_sleep(1);
    }
    __syncthreads();
    __threadfence();
}

// ---------------------------------------------------------------------------
// xh0 GEMM via fp16 MFMA: xh0[3200][1024] = x16[3200][256] @ wxT[1024][256]^T
// ---------------------------------------------------------------------------
#define PM 128
#define PN 128
#define PK 64

__global__ __launch_bounds__(256) void gemm16_mfma(
    const _Float16* __restrict__ A16,   // [3200][256]
    const _Float16* __restrict__ B16,   // [1024][256]
    float* __restrict__ C)              // [3200][1024]
{
    __shared__ __align__(16) _Float16 Asub[PM * PK];
    __shared__ __align__(16) _Float16 Bsub[PN * PK];

    const int tid = threadIdx.x;
    const int l = tid & 63;
    const int w = tid >> 6;
    const int wm = w >> 1, wn = w & 1;

    const int n0 = blockIdx.x * PN;
    const int m0 = blockIdx.y * PM;

    f32x4 acc[4][4] = {};

    for (int k0 = 0; k0 < H_; k0 += PK) {
#pragma unroll
        for (int is = 0; is < 4; ++is) {
            const int i = is * 256 + tid;
            const int r = i >> 3;
            const int ch = (i & 7) ^ (r & 7);
            gload_lds16(A16 + (size_t)(m0 + r) * H_ + k0 + ch * 8, &Asub[i * 8]);
            gload_lds16(B16 + (size_t)(n0 + r) * H_ + k0 + ch * 8, &Bsub[i * 8]);
        }
        __syncthreads();

#pragma unroll
        for (int ks = 0; ks < 2; ++ks) {
            f16x8 af[4], bf[4];
#pragma unroll
            for (int i = 0; i < 4; ++i) {
                const int r = wm * 64 + i * 16 + (l & 15);
                const int ch = (ks * 4 + (l >> 4)) ^ (r & 7);
                af[i] = *reinterpret_cast<const f16x8*>(&Asub[r * PK + ch * 8]);
            }
#pragma unroll
            for (int jf = 0; jf < 4; ++jf) {
                const int r = wn * 64 + jf * 16 + (l & 15);
                const int ch = (ks * 4 + (l >> 4)) ^ (r & 7);
                bf[jf] = *reinterpret_cast<const f16x8*>(&Bsub[r * PK + ch * 8]);
            }
#pragma unroll
            for (int i = 0; i < 4; ++i)
#pragma unroll
                for (int jf = 0; jf < 4; ++jf)
                    acc[i][jf] = __builtin_amdgcn_mfma_f32_16x16x32_f16(
                        af[i], bf[jf], acc[i][jf], 0, 0, 0);
        }
        __syncthreads();
    }

    const int rb = (l >> 4) << 2;
    const int cl = l & 15;
#pragma unroll
    for (int jf = 0; jf < 4; ++jf) {
        const int col = n0 + wn * 64 + jf * 16 + cl;
#pragma unroll
        for (int i = 0; i < 4; ++i) {
            const int rowb = m0 + wm * 64 + i * 16 + rb;
#pragma unroll
            for (int r = 0; r < 4; ++r)
                C[(size_t)(rowb + r) * G_ + col] = acc[i][jf][r];
        }
    }
}

// ---------------------------------------------------------------------------
// Column-partitioned persistent MI-LSTM recurrence (round-9/13 structure —
// threadfence exchange, measured 434 us; fenceless-atomic variant was 2.2x
// worse, round 15). 32 blocks x 256 threads; block c owns h-dims [8c,8c+8).
// ---------------------------------------------------------------------------
__global__ __launch_bounds__(256) void mi_rec(
    const _Float16* __restrict__ wpk,   // [32][3][32][256]
    const float* __restrict__ xh0,      // [T*B][G] fp32
    _Float16* __restrict__ h0x,         // [2][64][256]
    _Float16* __restrict__ h1x,         // [2][64][256]
    _Float16* __restrict__ outsH,       // [B*T][H] batch-major
    int* __restrict__ bars,             // padded slots, zeroed
    const float* __restrict__ alpha, const float* __restrict__ b1,
    const float* __restrict__ b2, const float* __restrict__ bsv)
{
    __shared__ __align__(16) _Float16 h0l[16384];
    __shared__ __align__(16) _Float16 h1l[16384];
    __shared__ __align__(16) _Float16 wl[24576];
    __shared__ float gA[2112], gB[2112];
    __shared__ float c0l[512], c1l[512];

    const int c = blockIdx.x;
    const int tid = threadIdx.x;
    const int l = tid & 63;
    const int w = tid >> 6;

    for (int i = tid; i < 2048; i += 256) {
        *reinterpret_cast<f16x8*>(&h0l[i << 3]) = f16x8{};
        *reinterpret_cast<f16x8*>(&h1l[i << 3]) = f16x8{};
    }
    for (int i = tid; i < 512; i += 256) { c0l[i] = 0.f; c1l[i] = 0.f; }

    for (int i = tid; i < 3072; i += 256) {
        const int m = i >> 10;
        const int col = (i >> 5) & 31;
        const int ch = i & 31;
        const f16x8 v = *reinterpret_cast<const f16x8*>(
            &wpk[(((size_t)c * 3 + m) * 32 + col) * 256 + (ch << 3)]);
        *reinterpret_cast<f16x8*>(
            &wl[(m * 32 + col) * 256 + ((ch ^ (col & 7)) << 3)]) = v;
    }

    const int u = tid & 7, b0 = tid >> 3;
    const int jl = (c << 3) + u;
    float al0[4], b10[4], b20[4], bs0[4], al1[4], b11[4], b21[4], bs1[4];
#pragma unroll
    for (int g = 0; g < 4; ++g) {
        const int col = (g << 8) + jl;
        al0[g] = alpha[col];        b10[g] = b1[col];
        b20[g] = b2[col];           bs0[g] = bsv[col];
        al1[g] = alpha[G_ + col];   b11[g] = b1[G_ + col];
        b21[g] = b2[G_ + col];      bs1[g] = bsv[G_ + col];
    }
    __syncthreads();

    const int arow = (w << 4) + (l & 15);
    const int cA = l & 15, cB = 16 + (l & 15);
    const int kq = l >> 4;

    auto MM = [&](const _Float16* am, const _Float16* bm, f32x4& A0, f32x4& A1) {
#pragma unroll
        for (int s = 0; s < 8; ++s) {
            const int ck = (s << 2) + kq;
            const f16x8 af = *reinterpret_cast<const f16x8*>(
                &am[(arow << 8) + ((ck ^ (arow & 7)) << 3)]);
            const f16x8 bf0 = *reinterpret_cast<const f16x8*>(
                &bm[(cA << 8) + ((ck ^ (cA & 7)) << 3)]);
            const f16x8 bf1 = *reinterpret_cast<const f16x8*>(
                &bm[(cB << 8) + ((ck ^ (cB & 7)) << 3)]);
            A0 = __builtin_amdgcn_mfma_f32_16x16x32_f16(af, bf0, A0, 0, 0, 0);
            A1 = __builtin_amdgcn_mfma_f32_16x16x32_f16(af, bf1, A1, 0, 0, 0);
        }
    };
    auto STG = [&](float* gl, f32x4 A0, f32x4 A1) {
        const int rb = (w << 4) + (kq << 2);
#pragma unroll
        for (int r = 0; r < 4; ++r) {
            gl[(rb + r) * 33 + cA] = A0[r];
            gl[(rb + r) * 33 + cB] = A1[r];
        }
    };
    auto STAGE_H = [&](const _Float16* src, _Float16* dst) {
#pragma unroll
        for (int it = 0; it < 8; ++it) {
            const int idx = (it << 8) + tid;
            const int row = idx >> 5, ch = idx & 31;
            const f16x8 v = *reinterpret_cast<const f16x8*>(&src[(row << 8) + (ch << 3)]);
            *reinterpret_cast<f16x8*>(&dst[(row << 8) + ((ch ^ (row & 7)) << 3)]) = v;
        }
    };

    for (int s = 0; s <= T_; ++s) {
        const int p = s & 1;
        _Float16* h0w = h0x + (p << 14);
        _Float16* h1w = h1x + (p << 14);

        if (s < T_) {
            // hoist xh0 loads (hide L3 latency under MM)
            float xv[2][4];
#pragma unroll
            for (int bb = 0; bb < 2; ++bb)
#pragma unroll
                for (int g = 0; g < 4; ++g)
                    xv[bb][g] = xh0[(((size_t)(s * B_ + (b0 + (bb << 5)))) << 10)
                                    + (g << 8) + jl];

            f32x4 A0 = {}, A1 = {};
            MM(h0l, wl, A0, A1);                 // Uh0
            STG(gA, A0, A1);
            __syncthreads();
#pragma unroll
            for (int bb = 0; bb < 2; ++bb) {
                const int b = b0 + (bb << 5);
                float g4[4];
#pragma unroll
                for (int g = 0; g < 4; ++g) {
                    const float a = gA[b * 33 + (g << 3) + u];
                    const float x = xv[bb][g];
                    g4[g] = al0[g] * x * a + b10[g] * x + b20[g] * a + bs0[g];
                }
                const float cn = c0l[(b << 3) + u] * sigm(g4[2] + 1.f)
                               + sigm(g4[0]) * tanhf(g4[1]);
                c0l[(b << 3) + u] = cn;
                h0w[(b << 8) + jl] = (_Float16)(tanhf(cn) * sigm(g4[3]));
            }
            __syncthreads();
        }

        if (s > 0) {
            f32x4 X0 = {}, X1 = {}, H0 = {}, H1 = {};
            MM(h0l, wl + 1 * 8192, X0, X1);      // Wx1 * h0(s-1)
            MM(h1l, wl + 2 * 8192, H0, H1);      // Uh1 * h1(s-2)
            STG(gA, X0, X1);
            STG(gB, H0, H1);
            __syncthreads();
#pragma unroll
            for (int bb = 0; bb < 2; ++bb) {
                const int b = b0 + (bb << 5);
                float g4[4];
#pragma unroll
                for (int g = 0; g < 4; ++g) {
                    const float xa = gA[b * 33 + (g << 3) + u];
                    const float ha = gB[b * 33 + (g << 3) + u];
                    g4[g] = al1[g] * xa * ha + b11[g] * xa + b21[g] * ha + bs1[g];
                }
                const float cn = c1l[(b << 3) + u] * sigm(g4[2] + 1.f)
                               + sigm(g4[0]) * tanhf(g4[1]);
                c1l[(b << 3) + u] = cn;
                const float hn = tanhf(cn) * sigm(g4[3]);
                h1w[(b << 8) + jl] = (_Float16)hn;
                outsH[(((size_t)b * T_ + (s - 1)) << 8) + jl] = (_Float16)hn;
            }
        }

        if (s < T_) {
            gbar_arrive(bars + s * BSTRIDE);
            gbar_wait_fast(bars + s * BSTRIDE);
            STAGE_H(h0w, h0l);
            if (s > 0) STAGE_H(h1w, h1l);
            __syncthreads();
        }
    }
}

// ---------------------------------------------------------------------------
// Projection: out[3200][50000] = outsH @ w16^T + sb.  fp16 MFMA, 128x128 tile.
// grid (391, 25): x = nt fastest (round-9 orientation, best measured).
// ---------------------------------------------------------------------------
__global__ __launch_bounds__(256) void proj_mfma(
    const _Float16* __restrict__ A16,   // [3200][256]
    const _Float16* __restrict__ B16,   // [50000][256]
    const float* __restrict__ bias,     // [50000]
    float* __restrict__ C)              // [3200][50000]
{
    __shared__ __align__(16) _Float16 Asub[PM * PK];
    __shared__ __align__(16) _Float16 Bsub[PN * PK];

    const int tid = threadIdx.x;
    const int l = tid & 63;
    const int w = tid >> 6;
    const int wm = w >> 1, wn = w & 1;

    const int n0 = blockIdx.x * PN;     // nt fastest
    const int m0 = blockIdx.y * PM;

    f32x4 acc[4][4] = {};

    for (int k0 = 0; k0 < H_; k0 += PK) {
#pragma unroll
        for (int is = 0; is < 4; ++is) {
            const int i = is * 256 + tid;
            const int r = i >> 3;
            const int ch = (i & 7) ^ (r & 7);
            gload_lds16(A16 + (size_t)(m0 + r) * H_ + k0 + ch * 8, &Asub[i * 8]);
            int n = n0 + r; if (n > V_ - 1) n = V_ - 1;
            gload_lds16(B16 + (size_t)n * H_ + k0 + ch * 8, &Bsub[i * 8]);
        }
        __syncthreads();

#pragma unroll
        for (int ks = 0; ks < 2; ++ks) {
            f16x8 af[4], bf[4];
#pragma unroll
            for (int i = 0; i < 4; ++i) {
                const int r = wm * 64 + i * 16 + (l & 15);
                const int ch = (ks * 4 + (l >> 4)) ^ (r & 7);
                af[i] = *reinterpret_cast<const f16x8*>(&Asub[r * PK + ch * 8]);
            }
#pragma unroll
            for (int jf = 0; jf < 4; ++jf) {
                const int r = wn * 64 + jf * 16 + (l & 15);
                const int ch = (ks * 4 + (l >> 4)) ^ (r & 7);
                bf[jf] = *reinterpret_cast<const f16x8*>(&Bsub[r * PK + ch * 8]);
            }
#pragma unroll
            for (int i = 0; i < 4; ++i)
#pragma unroll
                for (int jf = 0; jf < 4; ++jf)
                    acc[i][jf] = __builtin_amdgcn_mfma_f32_16x16x32_f16(
                        af[i], bf[jf], acc[i][jf], 0, 0, 0);
        }
        __syncthreads();
    }

    const int rb = (l >> 4) << 2;
    const int cl = l & 15;
#pragma unroll
    for (int jf = 0; jf < 4; ++jf) {
        const int col = n0 + wn * 64 + jf * 16 + cl;
        if (col < V_) {
            const float bv = bias[col];
#pragma unroll
            for (int i = 0; i < 4; ++i) {
                const int rowb = m0 + wm * 64 + i * 16 + rb;
#pragma unroll
                for (int r = 0; r < 4; ++r)
                    C[(size_t)(rowb + r) * V_ + col] = acc[i][jf][r] + bv;
            }
        }
    }
}

// ---------------------------------------------------------------------------
extern "C" void kernel_launch(void* const* d_in, const int* in_sizes, int n_in,
                              void* d_out, int out_size, void* d_ws, size_t ws_size,
                              hipStream_t stream)
{
    const int*   idx   = (const int*)  d_in[0];
    const float* emb   = (const float*)d_in[1];
    const float* Wx    = (const float*)d_in[2];   // [2][256][1024]
    const float* Uh    = (const float*)d_in[3];   // [2][256][1024]
    const float* alpha = (const float*)d_in[4];   // [2][1024]
    const float* b1    = (const float*)d_in[5];
    const float* b2    = (const float*)d_in[6];
    const float* bsv   = (const float*)d_in[7];
    const float* sw    = (const float*)d_in[8];   // [50000][256]
    const float* sb    = (const float*)d_in[9];   // [50000]
    float* out = (float*)d_out;

    // workspace layout (bytes)
    char* wsb = (char*)d_ws;
    _Float16* x16   = (_Float16*)(wsb);                 //  1,638,400
    float*    xh0   = (float*)   (wsb + 1638400);       // 13,107,200
    _Float16* outsH = (_Float16*)(wsb + 14745600);      //  1,638,400
    _Float16* w16   = (_Float16*)(wsb + 16384000);      // 25,600,000
    _Float16* wxT   = (_Float16*)(wsb + 41984000);      //    524,288
    _Float16* wpk   = (_Float16*)(wsb + 42508288);      //  1,572,864
    _Float16* h0x   = (_Float16*)(wsb + 44081152);      //     65,536
    _Float16* h1x   = (_Float16*)(wsb + 44146688);      //     65,536
    int*      bars  = (int*)     (wsb + 44212224);      //     16,384

    const float* Wx0 = Wx;
    const float* Wx1 = Wx + (size_t)H_ * G_;
    const float* Uh0 = Uh;
    const float* Uh1 = Uh + (size_t)H_ * G_;

    // zero barrier slots (must precede mi_rec every call)
    (void)hipMemsetAsync(bars, 0, 16384, stream);

    // 0) pack recurrence weights + transpose-pack Wx0 + w16 convert
    {
        dim3 grid(NBLK, 3);
        pack_w_rec<<<grid, 256, 0, stream>>>(Uh0, Wx1, Uh1, wpk);
    }
    {
        dim3 grid(4, 16);
        pack_wx0<<<grid, 256, 0, stream>>>(Wx0, wxT);
    }
    conv_half<<<(V_ * H_) / 2048, 256, 0, stream>>>(sw, w16, V_ * H_);

    // 1) embedding gather -> fp16 (time-major)
    embed_k<<<T_ * B_, 64, 0, stream>>>(idx, emb, x16);

    // 2) xh0 = x16 @ wxT^T  (fp16 MFMA, fp32 out)
    {
        dim3 grid(G_ / PN, 3200 / PM);   // (8, 25)
        gemm16_mfma<<<grid, 256, 0, stream>>>(x16, wxT, xh0);
    }

    // 3) recurrence: 32-block cooperative persistent kernel
    mi_rec<<<NBLK, 256, 0, stream>>>(wpk, xh0, h0x, h1x, outsH, bars,
                                     alpha, b1, b2, bsv);

    // 4) logits = outsH @ w16^T + sb (nt-fastest grid)
    {
        dim3 grid((V_ + PN - 1) / PN, 3200 / PM);   // (391, 25)
        proj_mfma<<<grid, 256, 0, stream>>>(outsH, w16, sb, out);
    }
}

// Round 17
// 677.826 us; speedup vs baseline: 1.8720x; 1.0218x over previous
//
#include <hip/hip_runtime.h>
#include <hip/hip_bf16.h>
#include <math.h>

// Problem constants
#define B_ 64
#define T_ 50
#define H_ 256
#define G_ 1024
#define V_ 50000
#define NBLK 32
#define BSTRIDE 64                      // ints per barrier slot (256B line)

using f16x8 = __attribute__((ext_vector_type(8))) _Float16;
using f16x4 = __attribute__((ext_vector_type(4))) _Float16;
using f32x4 = __attribute__((ext_vector_type(4))) float;

__device__ __forceinline__ float sigm(float x) { return 1.0f / (1.0f + expf(-x)); }

// ---------------------------------------------------------------------------
// Embedding gather -> fp16, time-major: x16[t*B + b][h]
// ---------------------------------------------------------------------------
__global__ __launch_bounds__(64) void embed_k(const int* __restrict__ idx,
                                              const float* __restrict__ emb,
                                              _Float16* __restrict__ x16)
{
    const int row = blockIdx.x;          // t*B + b
    const int b = row & (B_ - 1);
    const int t = row >> 6;
    const int id = idx[b * T_ + t];
    const float4 v = *reinterpret_cast<const float4*>(emb + (size_t)id * H_ + threadIdx.x * 4);
    f16x4 h;
    h[0] = (_Float16)v.x; h[1] = (_Float16)v.y;
    h[2] = (_Float16)v.z; h[3] = (_Float16)v.w;
    *reinterpret_cast<f16x4*>(x16 + (size_t)row * H_ + threadIdx.x * 4) = h;
}

// ---------------------------------------------------------------------------
// fp32 -> fp16 convert (8 elems/thread), n multiple of 2048
// ---------------------------------------------------------------------------
__global__ __launch_bounds__(256) void conv_half(const float* __restrict__ in,
                                                 _Float16* __restrict__ out, int n)
{
    const int i = (blockIdx.x * 256 + threadIdx.x) * 8;
    if (i + 8 <= n) {
        const float4 v0 = *reinterpret_cast<const float4*>(in + i);
        const float4 v1 = *reinterpret_cast<const float4*>(in + i + 4);
        f16x8 h;
        h[0] = (_Float16)v0.x; h[1] = (_Float16)v0.y;
        h[2] = (_Float16)v0.z; h[3] = (_Float16)v0.w;
        h[4] = (_Float16)v1.x; h[5] = (_Float16)v1.y;
        h[6] = (_Float16)v1.z; h[7] = (_Float16)v1.w;
        *reinterpret_cast<f16x8*>(out + i) = h;
    }
}

// ---------------------------------------------------------------------------
// Transpose-pack Wx[0] [256][1024] fp32 -> wxT [1024][256] fp16.
// ---------------------------------------------------------------------------
__global__ __launch_bounds__(256) void pack_wx0(const float* __restrict__ Wx0,
                                                _Float16* __restrict__ wxT)
{
    __shared__ _Float16 ts[64][65];
    const int k0 = blockIdx.x * 64;
    const int n0 = blockIdx.y * 64;
    const int tr = threadIdx.x >> 6;     // 0..3
    const int tc = threadIdx.x & 63;
#pragma unroll
    for (int i = 0; i < 16; ++i) {
        const int r = i * 4 + tr;
        ts[r][tc] = (_Float16)Wx0[(size_t)(k0 + r) * G_ + n0 + tc];
    }
    __syncthreads();
#pragma unroll
    for (int i = 0; i < 16; ++i) {
        const int c = i * 4 + tr;
        wxT[(size_t)(n0 + c) * H_ + k0 + tc] = ts[tc][c];
    }
}

// ---------------------------------------------------------------------------
// Pack recurrence weights for column-partitioned blocks.
// ---------------------------------------------------------------------------
__global__ __launch_bounds__(256) void pack_w_rec(const float* __restrict__ Uh0,
                                                  const float* __restrict__ Wx1,
                                                  const float* __restrict__ Uh1,
                                                  _Float16* __restrict__ wpk)
{
    const int c = blockIdx.x;            // 0..31
    const int m = blockIdx.y;            // 0..2
    const float* __restrict__ src = (m == 0) ? Uh0 : (m == 1) ? Wx1 : Uh1;
    _Float16* __restrict__ dst = wpk + (((size_t)c * 3 + m) << 13);
    for (int i = threadIdx.x; i < 8192; i += 256) {
        const int k = i >> 5;
        const int col = i & 31;
        const int colg = ((col >> 3) << 8) + (c << 3) + (col & 7);
        dst[(col << 8) + k] = (_Float16)src[(size_t)k * G_ + colg];
    }
}

// ---------------------------------------------------------------------------
__device__ __forceinline__ void gload_lds16(const void* g, void* l)
{
    __builtin_amdgcn_global_load_lds(
        (const __attribute__((address_space(1))) unsigned int*)g,
        (__attribute__((address_space(3))) unsigned int*)l, 16, 0, 0);
}

// Barrier slots padded: slot s at bars + s*BSTRIDE.
__device__ __forceinline__ void gbar_arrive(int* slot)
{
    __syncthreads();
    if (threadIdx.x == 0) {
        __threadfence();
        __hip_atomic_fetch_add(slot, 1, __ATOMIC_RELAXED, __HIP_MEMORY_SCOPE_AGENT);
    }
}

__device__ __forceinline__ void gbar_wait_fast(int* slot)
{
    if (threadIdx.x == 0) {
        while (__hip_atomic_load(slot, __ATOMIC_RELAXED, __HIP_MEMORY_SCOPE_AGENT) < NBLK)
            __builtin_amdgcn_s_sleep(1);
    }
    __syncthreads();
    __threadfence();
}

// ---------------------------------------------------------------------------
// xh0 GEMM via fp16 MFMA: xh0[3200][1024] = x16[3200][256] @ wxT[1024][256]^T
// ---------------------------------------------------------------------------
#define PM 128
#define PN 128
#define PK 64

__global__ __launch_bounds__(256) void gemm16_mfma(
    const _Float16* __restrict__ A16,   // [3200][256]
    const _Float16* __restrict__ B16,   // [1024][256]
    float* __restrict__ C)              // [3200][1024]
{
    __shared__ __align__(16) _Float16 Asub[PM * PK];
    __shared__ __align__(16) _Float16 Bsub[PN * PK];

    const int tid = threadIdx.x;
    const int l = tid & 63;
    const int w = tid >> 6;
    const int wm = w >> 1, wn = w & 1;

    const int n0 = blockIdx.x * PN;
    const int m0 = blockIdx.y * PM;

    f32x4 acc[4][4] = {};

    for (int k0 = 0; k0 < H_; k0 += PK) {
#pragma unroll
        for (int is = 0; is < 4; ++is) {
            const int i = is * 256 + tid;
            const int r = i >> 3;
            const int ch = (i & 7) ^ (r & 7);
            gload_lds16(A16 + (size_t)(m0 + r) * H_ + k0 + ch * 8, &Asub[i * 8]);
            gload_lds16(B16 + (size_t)(n0 + r) * H_ + k0 + ch * 8, &Bsub[i * 8]);
        }
        __syncthreads();

#pragma unroll
        for (int ks = 0; ks < 2; ++ks) {
            f16x8 af[4], bf[4];
#pragma unroll
            for (int i = 0; i < 4; ++i) {
                const int r = wm * 64 + i * 16 + (l & 15);
                const int ch = (ks * 4 + (l >> 4)) ^ (r & 7);
                af[i] = *reinterpret_cast<const f16x8*>(&Asub[r * PK + ch * 8]);
            }
#pragma unroll
            for (int jf = 0; jf < 4; ++jf) {
                const int r = wn * 64 + jf * 16 + (l & 15);
                const int ch = (ks * 4 + (l >> 4)) ^ (r & 7);
                bf[jf] = *reinterpret_cast<const f16x8*>(&Bsub[r * PK + ch * 8]);
            }
#pragma unroll
            for (int i = 0; i < 4; ++i)
#pragma unroll
                for (int jf = 0; jf < 4; ++jf)
                    acc[i][jf] = __builtin_amdgcn_mfma_f32_16x16x32_f16(
                        af[i], bf[jf], acc[i][jf], 0, 0, 0);
        }
        __syncthreads();
    }

    const int rb = (l >> 4) << 2;
    const int cl = l & 15;
#pragma unroll
    for (int jf = 0; jf < 4; ++jf) {
        const int col = n0 + wn * 64 + jf * 16 + cl;
#pragma unroll
        for (int i = 0; i < 4; ++i) {
            const int rowb = m0 + wm * 64 + i * 16 + rb;
#pragma unroll
            for (int r = 0; r < 4; ++r)
                C[(size_t)(rowb + r) * G_ + col] = acc[i][jf][r];
        }
    }
}

// ---------------------------------------------------------------------------
// Column-partitioned persistent MI-LSTM recurrence (round-9/13 structure —
// threadfence exchange, measured 430 us floor). 32 blocks x 256 threads.
// ---------------------------------------------------------------------------
__global__ __launch_bounds__(256) void mi_rec(
    const _Float16* __restrict__ wpk,   // [32][3][32][256]
    const float* __restrict__ xh0,      // [T*B][G] fp32
    _Float16* __restrict__ h0x,         // [2][64][256]
    _Float16* __restrict__ h1x,         // [2][64][256]
    _Float16* __restrict__ outsH,       // [B*T][H] batch-major
    int* __restrict__ bars,             // padded slots, zeroed
    const float* __restrict__ alpha, const float* __restrict__ b1,
    const float* __restrict__ b2, const float* __restrict__ bsv)
{
    __shared__ __align__(16) _Float16 h0l[16384];
    __shared__ __align__(16) _Float16 h1l[16384];
    __shared__ __align__(16) _Float16 wl[24576];
    __shared__ float gA[2112], gB[2112];
    __shared__ float c0l[512], c1l[512];

    const int c = blockIdx.x;
    const int tid = threadIdx.x;
    const int l = tid & 63;
    const int w = tid >> 6;

    for (int i = tid; i < 2048; i += 256) {
        *reinterpret_cast<f16x8*>(&h0l[i << 3]) = f16x8{};
        *reinterpret_cast<f16x8*>(&h1l[i << 3]) = f16x8{};
    }
    for (int i = tid; i < 512; i += 256) { c0l[i] = 0.f; c1l[i] = 0.f; }

    for (int i = tid; i < 3072; i += 256) {
        const int m = i >> 10;
        const int col = (i >> 5) & 31;
        const int ch = i & 31;
        const f16x8 v = *reinterpret_cast<const f16x8*>(
            &wpk[(((size_t)c * 3 + m) * 32 + col) * 256 + (ch << 3)]);
        *reinterpret_cast<f16x8*>(
            &wl[(m * 32 + col) * 256 + ((ch ^ (col & 7)) << 3)]) = v;
    }

    const int u = tid & 7, b0 = tid >> 3;
    const int jl = (c << 3) + u;
    float al0[4], b10[4], b20[4], bs0[4], al1[4], b11[4], b21[4], bs1[4];
#pragma unroll
    for (int g = 0; g < 4; ++g) {
        const int col = (g << 8) + jl;
        al0[g] = alpha[col];        b10[g] = b1[col];
        b20[g] = b2[col];           bs0[g] = bsv[col];
        al1[g] = alpha[G_ + col];   b11[g] = b1[G_ + col];
        b21[g] = b2[G_ + col];      bs1[g] = bsv[G_ + col];
    }
    __syncthreads();

    const int arow = (w << 4) + (l & 15);
    const int cA = l & 15, cB = 16 + (l & 15);
    const int kq = l >> 4;

    auto MM = [&](const _Float16* am, const _Float16* bm, f32x4& A0, f32x4& A1) {
#pragma unroll
        for (int s = 0; s < 8; ++s) {
            const int ck = (s << 2) + kq;
            const f16x8 af = *reinterpret_cast<const f16x8*>(
                &am[(arow << 8) + ((ck ^ (arow & 7)) << 3)]);
            const f16x8 bf0 = *reinterpret_cast<const f16x8*>(
                &bm[(cA << 8) + ((ck ^ (cA & 7)) << 3)]);
            const f16x8 bf1 = *reinterpret_cast<const f16x8*>(
                &bm[(cB << 8) + ((ck ^ (cB & 7)) << 3)]);
            A0 = __builtin_amdgcn_mfma_f32_16x16x32_f16(af, bf0, A0, 0, 0, 0);
            A1 = __builtin_amdgcn_mfma_f32_16x16x32_f16(af, bf1, A1, 0, 0, 0);
        }
    };
    auto STG = [&](float* gl, f32x4 A0, f32x4 A1) {
        const int rb = (w << 4) + (kq << 2);
#pragma unroll
        for (int r = 0; r < 4; ++r) {
            gl[(rb + r) * 33 + cA] = A0[r];
            gl[(rb + r) * 33 + cB] = A1[r];
        }
    };
    auto STAGE_H = [&](const _Float16* src, _Float16* dst) {
#pragma unroll
        for (int it = 0; it < 8; ++it) {
            const int idx = (it << 8) + tid;
            const int row = idx >> 5, ch = idx & 31;
            const f16x8 v = *reinterpret_cast<const f16x8*>(&src[(row << 8) + (ch << 3)]);
            *reinterpret_cast<f16x8*>(&dst[(row << 8) + ((ch ^ (row & 7)) << 3)]) = v;
        }
    };

    for (int s = 0; s <= T_; ++s) {
        const int p = s & 1;
        _Float16* h0w = h0x + (p << 14);
        _Float16* h1w = h1x + (p << 14);

        if (s < T_) {
            // hoist xh0 loads (hide L3 latency under MM)
            float xv[2][4];
#pragma unroll
            for (int bb = 0; bb < 2; ++bb)
#pragma unroll
                for (int g = 0; g < 4; ++g)
                    xv[bb][g] = xh0[(((size_t)(s * B_ + (b0 + (bb << 5)))) << 10)
                                    + (g << 8) + jl];

            f32x4 A0 = {}, A1 = {};
            MM(h0l, wl, A0, A1);                 // Uh0
            STG(gA, A0, A1);
            __syncthreads();
#pragma unroll
            for (int bb = 0; bb < 2; ++bb) {
                const int b = b0 + (bb << 5);
                float g4[4];
#pragma unroll
                for (int g = 0; g < 4; ++g) {
                    const float a = gA[b * 33 + (g << 3) + u];
                    const float x = xv[bb][g];
                    g4[g] = al0[g] * x * a + b10[g] * x + b20[g] * a + bs0[g];
                }
                const float cn = c0l[(b << 3) + u] * sigm(g4[2] + 1.f)
                               + sigm(g4[0]) * tanhf(g4[1]);
                c0l[(b << 3) + u] = cn;
                h0w[(b << 8) + jl] = (_Float16)(tanhf(cn) * sigm(g4[3]));
            }
            __syncthreads();
        }

        if (s > 0) {
            f32x4 X0 = {}, X1 = {}, H0 = {}, H1 = {};
            MM(h0l, wl + 1 * 8192, X0, X1);      // Wx1 * h0(s-1)
            MM(h1l, wl + 2 * 8192, H0, H1);      // Uh1 * h1(s-2)
            STG(gA, X0, X1);
            STG(gB, H0, H1);
            __syncthreads();
#pragma unroll
            for (int bb = 0; bb < 2; ++bb) {
                const int b = b0 + (bb << 5);
                float g4[4];
#pragma unroll
                for (int g = 0; g < 4; ++g) {
                    const float xa = gA[b * 33 + (g << 3) + u];
                    const float ha = gB[b * 33 + (g << 3) + u];
                    g4[g] = al1[g] * xa * ha + b11[g] * xa + b21[g] * ha + bs1[g];
                }
                const float cn = c1l[(b << 3) + u] * sigm(g4[2] + 1.f)
                               + sigm(g4[0]) * tanhf(g4[1]);
                c1l[(b << 3) + u] = cn;
                const float hn = tanhf(cn) * sigm(g4[3]);
                h1w[(b << 8) + jl] = (_Float16)hn;
                outsH[(((size_t)b * T_ + (s - 1)) << 8) + jl] = (_Float16)hn;
            }
        }

        if (s < T_) {
            gbar_arrive(bars + s * BSTRIDE);
            gbar_wait_fast(bars + s * BSTRIDE);
            STAGE_H(h0w, h0l);
            if (s > 0) STAGE_H(h1w, h1l);
            __syncthreads();
        }
    }
}

// ---------------------------------------------------------------------------
// Projection: out[3200][50000] = outsH @ w16^T + sb.  fp16 MFMA, 128x128 tile.
// grid (391, 25), nt fastest. Epilogue: LDS-transposed, two 64-row phases ->
// row-contiguous float4 stores (16 store instrs/thread instead of 64 scalar).
// tbuf aliases Asub/Bsub (34KB total LDS, occupancy unchanged).
// ---------------------------------------------------------------------------
__global__ __launch_bounds__(256) void proj_mfma(
    const _Float16* __restrict__ A16,   // [3200][256]
    const _Float16* __restrict__ B16,   // [50000][256]
    const float* __restrict__ bias,     // [50000]
    float* __restrict__ C)              // [3200][50000]
{
    __shared__ __align__(16) char smem[33792];   // max(Asub+Bsub, tbuf[64][132])
    _Float16* Asub = (_Float16*)smem;
    _Float16* Bsub = (_Float16*)(smem + 16384);
    float*    tbuf = (float*)smem;               // [64][132] after k-loop

    const int tid = threadIdx.x;
    const int l = tid & 63;
    const int w = tid >> 6;
    const int wm = w >> 1, wn = w & 1;

    const int n0 = blockIdx.x * PN;     // nt fastest
    const int m0 = blockIdx.y * PM;

    f32x4 acc[4][4] = {};

    for (int k0 = 0; k0 < H_; k0 += PK) {
#pragma unroll
        for (int is = 0; is < 4; ++is) {
            const int i = is * 256 + tid;
            const int r = i >> 3;
            const int ch = (i & 7) ^ (r & 7);
            gload_lds16(A16 + (size_t)(m0 + r) * H_ + k0 + ch * 8, &Asub[i * 8]);
            int n = n0 + r; if (n > V_ - 1) n = V_ - 1;
            gload_lds16(B16 + (size_t)n * H_ + k0 + ch * 8, &Bsub[i * 8]);
        }
        __syncthreads();

#pragma unroll
        for (int ks = 0; ks < 2; ++ks) {
            f16x8 af[4], bf[4];
#pragma unroll
            for (int i = 0; i < 4; ++i) {
                const int r = wm * 64 + i * 16 + (l & 15);
                const int ch = (ks * 4 + (l >> 4)) ^ (r & 7);
                af[i] = *reinterpret_cast<const f16x8*>(&Asub[r * PK + ch * 8]);
            }
#pragma unroll
            for (int jf = 0; jf < 4; ++jf) {
                const int r = wn * 64 + jf * 16 + (l & 15);
                const int ch = (ks * 4 + (l >> 4)) ^ (r & 7);
                bf[jf] = *reinterpret_cast<const f16x8*>(&Bsub[r * PK + ch * 8]);
            }
#pragma unroll
            for (int i = 0; i < 4; ++i)
#pragma unroll
                for (int jf = 0; jf < 4; ++jf)
                    acc[i][jf] = __builtin_amdgcn_mfma_f32_16x16x32_f16(
                        af[i], bf[jf], acc[i][jf], 0, 0, 0);
        }
        __syncthreads();
    }

    // ---- epilogue: two 64-row phases through LDS, coalesced float4 stores ----
    const int rbl = (l >> 4) << 2;      // 0,4,8,12
    const int cll = l & 15;
#pragma unroll
    for (int ph = 0; ph < 2; ++ph) {
        if (ph) __syncthreads();        // tbuf reuse guard between phases
        if (wm == ph) {
#pragma unroll
            for (int jf = 0; jf < 4; ++jf)
#pragma unroll
                for (int i = 0; i < 4; ++i)
#pragma unroll
                    for (int r = 0; r < 4; ++r)
                        tbuf[(i * 16 + rbl + r) * 132 + wn * 64 + jf * 16 + cll]
                            = acc[i][jf][r];
        }
        __syncthreads();
#pragma unroll
        for (int k = 0; k < 8; ++k) {
            const int f = k * 256 + tid;        // 0..2047
            const int lr = f >> 5;              // 0..63
            const int c4 = (f & 31) << 2;       // 0..124
            const int col = n0 + c4;
            if (col < V_) {
                float4 v = *reinterpret_cast<const float4*>(&tbuf[lr * 132 + c4]);
                const float4 bv = *reinterpret_cast<const float4*>(&bias[col]);
                v.x += bv.x; v.y += bv.y; v.z += bv.z; v.w += bv.w;
                *reinterpret_cast<float4*>(
                    &C[(size_t)(m0 + ph * 64 + lr) * V_ + col]) = v;
            }
        }
    }
}

// ---------------------------------------------------------------------------
extern "C" void kernel_launch(void* const* d_in, const int* in_sizes, int n_in,
                              void* d_out, int out_size, void* d_ws, size_t ws_size,
                              hipStream_t stream)
{
    const int*   idx   = (const int*)  d_in[0];
    const float* emb   = (const float*)d_in[1];
    const float* Wx    = (const float*)d_in[2];   // [2][256][1024]
    const float* Uh    = (const float*)d_in[3];   // [2][256][1024]
    const float* alpha = (const float*)d_in[4];   // [2][1024]
    const float* b1    = (const float*)d_in[5];
    const float* b2    = (const float*)d_in[6];
    const float* bsv   = (const float*)d_in[7];
    const float* sw    = (const float*)d_in[8];   // [50000][256]
    const float* sb    = (const float*)d_in[9];   // [50000]
    float* out = (float*)d_out;

    // workspace layout (bytes)
    char* wsb = (char*)d_ws;
    _Float16* x16   = (_Float16*)(wsb);                 //  1,638,400
    float*    xh0   = (float*)   (wsb + 1638400);       // 13,107,200
    _Float16* outsH = (_Float16*)(wsb + 14745600);      //  1,638,400
    _Float16* w16   = (_Float16*)(wsb + 16384000);      // 25,600,000
    _Float16* wxT   = (_Float16*)(wsb + 41984000);      //    524,288
    _Float16* wpk   = (_Float16*)(wsb + 42508288);      //  1,572,864
    _Float16* h0x   = (_Float16*)(wsb + 44081152);      //     65,536
    _Float16* h1x   = (_Float16*)(wsb + 44146688);      //     65,536
    int*      bars  = (int*)     (wsb + 44212224);      //     16,384

    const float* Wx0 = Wx;
    const float* Wx1 = Wx + (size_t)H_ * G_;
    const float* Uh0 = Uh;
    const float* Uh1 = Uh + (size_t)H_ * G_;

    // zero barrier slots (must precede mi_rec every call)
    (void)hipMemsetAsync(bars, 0, 16384, stream);

    // 0) pack recurrence weights + transpose-pack Wx0 + w16 convert
    {
        dim3 grid(NBLK, 3);
        pack_w_rec<<<grid, 256, 0, stream>>>(Uh0, Wx1, Uh1, wpk);
    }
    {
        dim3 grid(4, 16);
        pack_wx0<<<grid, 256, 0, stream>>>(Wx0, wxT);
    }
    conv_half<<<(V_ * H_) / 2048, 256, 0, stream>>>(sw, w16, V_ * H_);

    // 1) embedding gather -> fp16 (time-major)
    embed_k<<<T_ * B_, 64, 0, stream>>>(idx, emb, x16);

    // 2) xh0 = x16 @ wxT^T  (fp16 MFMA, fp32 out)
    {
        dim3 grid(G_ / PN, 3200 / PM);   // (8, 25)
        gemm16_mfma<<<grid, 256, 0, stream>>>(x16, wxT, xh0);
    }

    // 3) recurrence: 32-block cooperative persistent kernel
    mi_rec<<<NBLK, 256, 0, stream>>>(wpk, xh0, h0x, h1x, outsH, bars,
                                     alpha, b1, b2, bsv);

    // 4) logits = outsH @ w16^T + sb (nt-fastest grid, coalesced epilogue)
    {
        dim3 grid((V_ + PN - 1) / PN, 3200 / PM);   // (391, 25)
        proj_mfma<<<grid, 256, 0, stream>>>(outsH, w16, sb, out);
    }
}